// Round 16
// baseline (115.487 us; speedup 1.0000x reference)
//
#include <hip/hip_runtime.h>
#include <hip/hip_bf16.h>

// B=512, T=256, C=384, H=64 single-head causal attention.
// Round 15: R13 base + split B-ingest (LDS || L2).
//   GEMM: wave w rows [16w,16w+16) x 192 as in R13, but B cols 96..191 are
//   read from global bt (L2-hot, 1-chunk-ahead reg prefetch bpf[6]) while
//   cols 0..95 come from LDS. Halves the LDS-pipe B traffic (the measured
//   ~10x-over-MFMA bottleneck) without touching A traffic or tile shape.
//   Bt LDS staging shrinks to rows 0..95 (75 KB). Epilogue/attn = R13.

constexpr int BSZ  = 512;
constexpr int TT   = 256;
constexpr int CDIM = 384;
constexpr int HDIM = 64;
constexpr int NQKV = 192;
constexpr float SCALE = 0.051031036307982884f;  // 384^-0.5 (C, not head size)
constexpr int BTST = 392;   // Bt LDS row stride (784 B)

typedef __attribute__((ext_vector_type(8))) short bf16x8;
typedef __attribute__((ext_vector_type(4))) float f32x4;

__device__ inline unsigned short f2bf(float f) {
    __hip_bfloat16 h = __float2bfloat16(f);
    return *(unsigned short*)&h;
}
__device__ inline bf16x8 pack8(float4 a, float4 b) {
    unsigned short p[8] = { f2bf(a.x), f2bf(a.y), f2bf(a.z), f2bf(a.w),
                            f2bf(b.x), f2bf(b.y), f2bf(b.z), f2bf(b.w) };
    return *(bf16x8*)p;
}
__device__ inline unsigned cvtpk(float lo, float hi) {
    unsigned r;
    asm volatile("v_cvt_pk_bf16_f32 %0, %1, %2" : "=v"(r) : "v"(lo), "v"(hi));
    return r;
}
#define PLSWAP32(a, b) asm volatile("v_permlane32_swap_b32 %0, %1" : "+v"(a), "+v"(b))
#define PLSWAP16(a, b) asm volatile("v_permlane16_swap_b32 %0, %1" : "+v"(a), "+v"(b))

// ---------------- kernel 0: Bt[192][384] bf16 = [Wq|Wk|Wv]^T ----------------
__global__ __launch_bounds__(256) void prep_bt(
    const float* __restrict__ Wq, const float* __restrict__ Wk,
    const float* __restrict__ Wv, unsigned short* __restrict__ bt)
{
    int idx = blockIdx.x * 256 + threadIdx.x;
    if (idx >= NQKV * CDIM) return;
    int n = idx / CDIM, k = idx - n * CDIM;
    const float* W = (n < 64) ? Wq : (n < 128) ? Wk : Wv;
    bt[idx] = f2bf(W[(size_t)k * HDIM + (n & 63)]);
}

// ---------------- fused QKV-projection + flash attention ----------------
__global__ __launch_bounds__(1024) void fused(
    const float* __restrict__ x, const unsigned short* __restrict__ bt,
    float* __restrict__ out)
{
    // GEMM phase: smem = Bt rows 0..95 [96][392] (75,264 B)
    // attn phase overlay: qs[256][64] (q) | kl[256][64] | vt[64][256]
    __shared__ __align__(16) unsigned short smem[NQKV * BTST];
    unsigned short* btl = smem;
    unsigned short* qs  = smem;
    unsigned short* kl  = smem + 16384;
    unsigned short* vt  = smem + 32768;

    const int b = blockIdx.x, tid = threadIdx.x;
    const int w = tid >> 6, lane = tid & 63;
    const int lr = lane & 15, lk = lane >> 4;

    // ---- GEMM: wave w -> rows [16w,16w+16) x 192, K = 384 ----
    const float* xr0 = x + ((size_t)b * TT + 16 * w + lr) * CDIM + lk * 8;

    float4 pA[2], pB[2], pC[2];
    bf16x8 bpf[6];   // next-chunk B frags for cols 96..191 (from L2)
#define LDCH(P, ks) { \
    P[0] = *(const float4*)&xr0[(ks) * 32];     \
    P[1] = *(const float4*)&xr0[(ks) * 32 + 4]; }
#define LDB(ks) { \
    _Pragma("unroll") \
    for (int ni = 0; ni < 6; ++ni) \
        bpf[ni] = *(const bf16x8*) \
            &bt[(size_t)(96 + ni * 16 + lr) * CDIM + (ks) * 32 + lk * 8]; }
#define STEP(P, ks, cond) { \
    bf16x8 a = pack8(P[0], P[1]); \
    bf16x8 bcur[6]; \
    _Pragma("unroll") \
    for (int ni = 0; ni < 6; ++ni) bcur[ni] = bpf[ni]; \
    if (cond) LDCH(P, (ks) + 3); \
    if ((ks) < 11) LDB((ks) + 1); \
    _Pragma("unroll") \
    for (int ni = 0; ni < 6; ++ni) { \
        bf16x8 bb = *(const bf16x8*)&btl[(ni * 16 + lr) * BTST + (ks) * 32 + lk * 8]; \
        acc[ni]     = __builtin_amdgcn_mfma_f32_16x16x32_bf16(a, bb,       acc[ni],     0, 0, 0); \
        acc[6 + ni] = __builtin_amdgcn_mfma_f32_16x16x32_bf16(a, bcur[ni], acc[6 + ni], 0, 0, 0); \
    } }

    // issue chunks 0..2 (A) + chunk 0 (B-hi) before Bt staging
    LDCH(pA, 0) LDCH(pB, 1) LDCH(pC, 2)
    LDB(0)

    // ---- stage Bt rows 0..95 into LDS: 4608 uint4, coalesced ----
    for (int i = tid; i < 96 * 48; i += 1024) {
        int row = i / 48, c8 = i - row * 48;
        *(uint4*)&btl[row * BTST + c8 * 8] = ((const uint4*)bt)[i];
    }
    __syncthreads();

    f32x4 acc[12];
    #pragma unroll
    for (int ni = 0; ni < 12; ++ni) acc[ni] = (f32x4){0.f, 0.f, 0.f, 0.f};

    #pragma unroll
    for (int kk = 0; kk < 4; ++kk) {
        STEP(pA, 3 * kk + 0, kk < 3)
        STEP(pB, 3 * kk + 1, kk < 3)
        STEP(pC, 3 * kk + 2, kk < 3)
    }
#undef LDCH
#undef LDB
#undef STEP
    __syncthreads();   // all Bt reads done before overlay writes

    // ---- epilogue: D-frags -> LDS homes. D: col=ni*16+lr, rowIn16=lk*4+r ----
    unsigned short* pq = qs + w * 1024;   // wave-private 16x64 (q staging)
    #pragma unroll
    for (int ni = 0; ni < 4; ++ni)        // q: cols 0..63, pre-scaled
        #pragma unroll
        for (int r = 0; r < 4; ++r) {
            int qr = lk * 4 + r;
            int h  = ni * 16 + lr;
            pq[qr * 64 + (h ^ ((qr & 7) << 3))] = f2bf(acc[ni][r] * SCALE);
        }
    #pragma unroll
    for (int ni = 4; ni < 8; ++ni)        // k: cols 64..127 -> kl[t][h] swz
        #pragma unroll
        for (int r = 0; r < 4; ++r) {
            int row = 16 * w + lk * 4 + r;
            int c2  = (ni - 4) * 16 + lr;
            kl[row * 64 + (c2 ^ ((row & 7) << 3))] = f2bf(acc[ni][r]);
        }
    #pragma unroll
    for (int ni = 8; ni < 12; ++ni) {     // v: cols 128..191 -> vt[h][t] swz
        int h  = (ni - 8) * 16 + lr;
        int t0 = 16 * w + lk * 4;
        unsigned short pk[4];
        #pragma unroll
        for (int r = 0; r < 4; ++r) pk[r] = f2bf(acc[ni][r]);
        *(uint2*)&vt[h * 256 + (t0 ^ ((h & 7) << 3))] = *(uint2*)pk;
    }
    __syncthreads();

    // ---- attention: wave w owns q-rows [16w,16w+16) ----
    const int q0 = 16 * w;
    bf16x8 qa[2];
    #pragma unroll
    for (int kc = 0; kc < 2; ++kc)
        qa[kc] = *(const bf16x8*)&pq[lr * 64 + ((kc * 32 + lk * 8) ^ ((lr & 7) << 3))];

    f32x4 oacc[4];
    float mrowL = -INFINITY;   // per-lane stats, q = q0 + lr
    float lpart = 0.f;
    float mrowT[4];            // transposed stats, q = q0 + lk*4 + r
    #pragma unroll
    for (int nh = 0; nh < 4; ++nh) oacc[nh] = (f32x4){0.f, 0.f, 0.f, 0.f};
    #pragma unroll
    for (int r = 0; r < 4; ++r) mrowT[r] = -INFINITY;

    const int lastt = w >> 2;
    for (int st = 0; st <= lastt; ++st) {
        // S^T = K Q^T: D[s][q]; lane holds q=lr, s = st*64 + ni*16 + lk*4 + r
        f32x4 sa[4];
        #pragma unroll
        for (int ni = 0; ni < 4; ++ni) sa[ni] = (f32x4){0.f, 0.f, 0.f, 0.f};
        #pragma unroll
        for (int ni = 0; ni < 4; ++ni) {
            int row = st * 64 + ni * 16 + lr;
            #pragma unroll
            for (int kc = 0; kc < 2; ++kc) {
                bf16x8 kb = *(const bf16x8*)
                    &kl[row * 64 + ((kc * 32 + lk * 8) ^ ((row & 7) << 3))];
                sa[ni] = __builtin_amdgcn_mfma_f32_16x16x32_bf16(kb, qa[kc], sa[ni], 0, 0, 0);
            }
        }
        // causal mask (diagonal tile only): s > q
        if (st == lastt) {
            #pragma unroll
            for (int ni = 0; ni < 4; ++ni) {
                #pragma unroll
                for (int r = 0; r < 4; ++r) {
                    int sg = st * 64 + ni * 16 + lk * 4 + r;
                    if (sg > q0 + lr) sa[ni][r] = -INFINITY;
                }
            }
        }
        // per-lane row max (16 in-lane values) + 2-round cross-lk reduce
        float pm = sa[0][0];
        #pragma unroll
        for (int ni = 0; ni < 4; ++ni)
            #pragma unroll
            for (int r = 0; r < 4; ++r) pm = fmaxf(pm, sa[ni][r]);
        pm = fmaxf(pm, __shfl_xor(pm, 16));
        pm = fmaxf(pm, __shfl_xor(pm, 32));
        float mn = fmaxf(mrowL, pm);
        float corr = __expf(mrowL - mn);   // exp(-inf)=0 first time
        mrowL = mn;
        lpart *= corr;
        // P = exp(S - m), per-lane l partial
        #pragma unroll
        for (int ni = 0; ni < 4; ++ni)
            #pragma unroll
            for (int r = 0; r < 4; ++r) {
                float p = __expf(sa[ni][r] - mn);
                sa[ni][r] = p;
                lpart += p;
            }
        // transposed rescale of oacc (oacc rows are q = q0 + lk*4 + r)
        #pragma unroll
        for (int r = 0; r < 4; ++r) {
            float mt = __shfl(mn, lk * 4 + r);   // lane lk*4+r has q=that index
            float ct = __expf(mrowT[r] - mt);
            mrowT[r] = mt;
            #pragma unroll
            for (int nh = 0; nh < 4; ++nh) oacc[nh][r] *= ct;
        }
        // pack P to bf16 words: Wp[ni][h] = {s=16ni+4lk+2h, +1} at q=lr
        unsigned Wp[4][2];
        #pragma unroll
        for (int ni = 0; ni < 4; ++ni) {
            Wp[ni][0] = cvtpk(sa[ni][0], sa[ni][1]);
            Wp[ni][1] = cvtpk(sa[ni][2], sa[ni][3]);
        }
        // permute to PV A-frags: pa[kc] word g = P[q=lr][s=32kc+8lk+2g..+1]
        bf16x8 pa[2];
        #pragma unroll
        for (int kc = 0; kc < 2; ++kc) {
            unsigned x0 = Wp[2 * kc][0], y0 = Wp[2 * kc + 1][0];
            PLSWAP32(x0, y0); PLSWAP16(x0, y0);   // x0 -> g0, y0 -> g2
            unsigned x1 = Wp[2 * kc][1], y1 = Wp[2 * kc + 1][1];
            PLSWAP32(x1, y1); PLSWAP16(x1, y1);   // x1 -> g1, y1 -> g3
            unsigned wq[4] = {x0, x1, y0, y1};
            pa[kc] = *(bf16x8*)wq;
        }
        // PV: A = pa (P rows=q), B = V^T  -> D[q=lk*4+r][h=nh*16+lr]
        #pragma unroll
        for (int nh = 0; nh < 4; ++nh) {
            int hrow = nh * 16 + lr;
            #pragma unroll
            for (int kc = 0; kc < 2; ++kc) {
                bf16x8 vb = *(const bf16x8*)
                    &vt[hrow * 256 + ((st * 64 + kc * 32 + lk * 8) ^ ((hrow & 7) << 3))];
                oacc[nh] = __builtin_amdgcn_mfma_f32_16x16x32_bf16(pa[kc], vb, oacc[nh], 0, 0, 0);
            }
        }
    }

    // ---- finalize: reduce per-lane l over lk, transpose, normalize ----
    float lsum = lpart;
    lsum += __shfl_xor(lsum, 16);
    lsum += __shfl_xor(lsum, 32);
    float linv[4];
    #pragma unroll
    for (int r = 0; r < 4; ++r)
        linv[r] = 1.0f / __shfl(lsum, lk * 4 + r);
    #pragma unroll
    for (int nh = 0; nh < 4; ++nh)
        #pragma unroll
        for (int r = 0; r < 4; ++r) {
            size_t row = (size_t)b * TT + q0 + lk * 4 + r;
            out[row * HDIM + nh * 16 + lr] = oacc[nh][r] * linv[r];
        }
}

extern "C" void kernel_launch(void* const* d_in, const int* in_sizes, int n_in,
                              void* d_out, int out_size, void* d_ws, size_t ws_size,
                              hipStream_t stream)
{
    const float* x  = (const float*)d_in[0];
    const float* Wq = (const float*)d_in[1];
    const float* Wk = (const float*)d_in[2];
    const float* Wv = (const float*)d_in[3];
    unsigned short* bt = (unsigned short*)d_ws;   // [192][384] bf16 = 147 KB
    float* out = (float*)d_out;

    prep_bt<<<(NQKV * CDIM + 255) / 256, 256, 0, stream>>>(Wq, Wk, Wv, bt);
    fused<<<BSZ, 1024, 0, stream>>>(x, bt, out);
}

// Round 17
// 61.411 us; speedup vs baseline: 1.8806x; 1.8806x over previous
//
#include <hip/hip_runtime.h>
#include <hip/hip_bf16.h>

// B=512, T=256, C=384, H=64 single-head causal attention.
// Round 16: restore Round-13 (best measured, 61.1 us). All structural
// variants tested R5-R15 came back null or negative; this is the plateau
// configuration.
//   GEMM: 16 waves, M=16/wave, acc[12] (48 VGPR), Bt in LDS, 3-deep ring,
//   no barriers in K-loop. Attn: swapped QK^T (mfma(K,Q)), per-lane softmax,
//   P via v_cvt_pk_bf16_f32 + v_permlane32/16_swap (no LDS for P).

constexpr int BSZ  = 512;
constexpr int TT   = 256;
constexpr int CDIM = 384;
constexpr int HDIM = 64;
constexpr int NQKV = 192;
constexpr float SCALE = 0.051031036307982884f;  // 384^-0.5 (C, not head size)
constexpr int BTST = 392;   // Bt LDS row stride (784 B)

typedef __attribute__((ext_vector_type(8))) short bf16x8;
typedef __attribute__((ext_vector_type(4))) float f32x4;

__device__ inline unsigned short f2bf(float f) {
    __hip_bfloat16 h = __float2bfloat16(f);
    return *(unsigned short*)&h;
}
__device__ inline bf16x8 pack8(float4 a, float4 b) {
    unsigned short p[8] = { f2bf(a.x), f2bf(a.y), f2bf(a.z), f2bf(a.w),
                            f2bf(b.x), f2bf(b.y), f2bf(b.z), f2bf(b.w) };
    return *(bf16x8*)p;
}
__device__ inline unsigned cvtpk(float lo, float hi) {
    unsigned r;
    asm volatile("v_cvt_pk_bf16_f32 %0, %1, %2" : "=v"(r) : "v"(lo), "v"(hi));
    return r;
}
#define PLSWAP32(a, b) asm volatile("v_permlane32_swap_b32 %0, %1" : "+v"(a), "+v"(b))
#define PLSWAP16(a, b) asm volatile("v_permlane16_swap_b32 %0, %1" : "+v"(a), "+v"(b))

// ---------------- kernel 0: Bt[192][384] bf16 = [Wq|Wk|Wv]^T ----------------
__global__ __launch_bounds__(256) void prep_bt(
    const float* __restrict__ Wq, const float* __restrict__ Wk,
    const float* __restrict__ Wv, unsigned short* __restrict__ bt)
{
    int idx = blockIdx.x * 256 + threadIdx.x;
    if (idx >= NQKV * CDIM) return;
    int n = idx / CDIM, k = idx - n * CDIM;
    const float* W = (n < 64) ? Wq : (n < 128) ? Wk : Wv;
    bt[idx] = f2bf(W[(size_t)k * HDIM + (n & 63)]);
}

// ---------------- fused QKV-projection + flash attention ----------------
__global__ __launch_bounds__(1024) void fused(
    const float* __restrict__ x, const unsigned short* __restrict__ bt,
    float* __restrict__ out)
{
    // GEMM phase: smem = Bt [192][392] (150,528 B)
    // attn phase overlay: qs[256][64] (q) | kl[256][64] | vt[64][256]
    __shared__ __align__(16) unsigned short smem[NQKV * BTST];
    unsigned short* btl = smem;
    unsigned short* qs  = smem;
    unsigned short* kl  = smem + 16384;
    unsigned short* vt  = smem + 32768;

    const int b = blockIdx.x, tid = threadIdx.x;
    const int w = tid >> 6, lane = tid & 63;
    const int lr = lane & 15, lk = lane >> 4;

    // ---- GEMM: wave w -> rows [16w,16w+16) x 192, K = 384 ----
    const float* xr0 = x + ((size_t)b * TT + 16 * w + lr) * CDIM + lk * 8;

    float4 pA[2], pB[2], pC[2];
#define LDCH(P, ks) { \
    P[0] = *(const float4*)&xr0[(ks) * 32];     \
    P[1] = *(const float4*)&xr0[(ks) * 32 + 4]; }
#define STEP(P, ks, cond) { \
    bf16x8 a = pack8(P[0], P[1]); \
    if (cond) LDCH(P, (ks) + 3); \
    _Pragma("unroll") \
    for (int ni = 0; ni < 12; ++ni) { \
        bf16x8 bb = *(const bf16x8*)&btl[(ni * 16 + lr) * BTST + (ks) * 32 + lk * 8]; \
        acc[ni] = __builtin_amdgcn_mfma_f32_16x16x32_bf16(a, bb, acc[ni], 0, 0, 0); \
    } }

    // issue chunks 0..2 before Bt staging: memory pipe busy from cycle 0
    LDCH(pA, 0) LDCH(pB, 1) LDCH(pC, 2)

    // ---- stage Bt into LDS: 9216 uint4, 9 per thread, coalesced ----
    #pragma unroll
    for (int p = 0; p < 9; ++p) {
        int i = p * 1024 + tid;
        int row = i / 48, c8 = i - row * 48;
        *(uint4*)&btl[row * BTST + c8 * 8] = ((const uint4*)bt)[i];
    }
    __syncthreads();

    f32x4 acc[12];
    #pragma unroll
    for (int ni = 0; ni < 12; ++ni) acc[ni] = (f32x4){0.f, 0.f, 0.f, 0.f};

    #pragma unroll
    for (int kk = 0; kk < 4; ++kk) {
        STEP(pA, 3 * kk + 0, kk < 3)
        STEP(pB, 3 * kk + 1, kk < 3)
        STEP(pC, 3 * kk + 2, kk < 3)
    }
#undef LDCH
#undef STEP
    __syncthreads();   // all Bt reads done before overlay writes

    // ---- epilogue: D-frags -> LDS homes. D: col=ni*16+lr, rowIn16=lk*4+r ----
    unsigned short* pq = qs + w * 1024;   // wave-private 16x64 (q staging)
    #pragma unroll
    for (int ni = 0; ni < 4; ++ni)        // q: cols 0..63, pre-scaled
        #pragma unroll
        for (int r = 0; r < 4; ++r) {
            int qr = lk * 4 + r;
            int h  = ni * 16 + lr;
            pq[qr * 64 + (h ^ ((qr & 7) << 3))] = f2bf(acc[ni][r] * SCALE);
        }
    #pragma unroll
    for (int ni = 4; ni < 8; ++ni)        // k: cols 64..127 -> kl[t][h] swz
        #pragma unroll
        for (int r = 0; r < 4; ++r) {
            int row = 16 * w + lk * 4 + r;
            int c2  = (ni - 4) * 16 + lr;
            kl[row * 64 + (c2 ^ ((row & 7) << 3))] = f2bf(acc[ni][r]);
        }
    #pragma unroll
    for (int ni = 8; ni < 12; ++ni) {     // v: cols 128..191 -> vt[h][t] swz
        int h  = (ni - 8) * 16 + lr;
        int t0 = 16 * w + lk * 4;
        unsigned short pk[4];
        #pragma unroll
        for (int r = 0; r < 4; ++r) pk[r] = f2bf(acc[ni][r]);
        *(uint2*)&vt[h * 256 + (t0 ^ ((h & 7) << 3))] = *(uint2*)pk;
    }
    __syncthreads();

    // ---- attention: wave w owns q-rows [16w,16w+16) ----
    const int q0 = 16 * w;
    bf16x8 qa[2];
    #pragma unroll
    for (int kc = 0; kc < 2; ++kc)
        qa[kc] = *(const bf16x8*)&pq[lr * 64 + ((kc * 32 + lk * 8) ^ ((lr & 7) << 3))];

    f32x4 oacc[4];
    float mrowL = -INFINITY;   // per-lane stats, q = q0 + lr
    float lpart = 0.f;
    float mrowT[4];            // transposed stats, q = q0 + lk*4 + r
    #pragma unroll
    for (int nh = 0; nh < 4; ++nh) oacc[nh] = (f32x4){0.f, 0.f, 0.f, 0.f};
    #pragma unroll
    for (int r = 0; r < 4; ++r) mrowT[r] = -INFINITY;

    const int lastt = w >> 2;
    for (int st = 0; st <= lastt; ++st) {
        // S^T = K Q^T: D[s][q]; lane holds q=lr, s = st*64 + ni*16 + lk*4 + r
        f32x4 sa[4];
        #pragma unroll
        for (int ni = 0; ni < 4; ++ni) sa[ni] = (f32x4){0.f, 0.f, 0.f, 0.f};
        #pragma unroll
        for (int ni = 0; ni < 4; ++ni) {
            int row = st * 64 + ni * 16 + lr;
            #pragma unroll
            for (int kc = 0; kc < 2; ++kc) {
                bf16x8 kb = *(const bf16x8*)
                    &kl[row * 64 + ((kc * 32 + lk * 8) ^ ((row & 7) << 3))];
                sa[ni] = __builtin_amdgcn_mfma_f32_16x16x32_bf16(kb, qa[kc], sa[ni], 0, 0, 0);
            }
        }
        // causal mask (diagonal tile only): s > q
        if (st == lastt) {
            #pragma unroll
            for (int ni = 0; ni < 4; ++ni) {
                #pragma unroll
                for (int r = 0; r < 4; ++r) {
                    int sg = st * 64 + ni * 16 + lk * 4 + r;
                    if (sg > q0 + lr) sa[ni][r] = -INFINITY;
                }
            }
        }
        // per-lane row max (16 in-lane values) + 2-round cross-lk reduce
        float pm = sa[0][0];
        #pragma unroll
        for (int ni = 0; ni < 4; ++ni)
            #pragma unroll
            for (int r = 0; r < 4; ++r) pm = fmaxf(pm, sa[ni][r]);
        pm = fmaxf(pm, __shfl_xor(pm, 16));
        pm = fmaxf(pm, __shfl_xor(pm, 32));
        float mn = fmaxf(mrowL, pm);
        float corr = __expf(mrowL - mn);   // exp(-inf)=0 first time
        mrowL = mn;
        lpart *= corr;
        // P = exp(S - m), per-lane l partial
        #pragma unroll
        for (int ni = 0; ni < 4; ++ni)
            #pragma unroll
            for (int r = 0; r < 4; ++r) {
                float p = __expf(sa[ni][r] - mn);
                sa[ni][r] = p;
                lpart += p;
            }
        // transposed rescale of oacc (oacc rows are q = q0 + lk*4 + r)
        #pragma unroll
        for (int r = 0; r < 4; ++r) {
            float mt = __shfl(mn, lk * 4 + r);   // lane lk*4+r has q=that index
            float ct = __expf(mrowT[r] - mt);
            mrowT[r] = mt;
            #pragma unroll
            for (int nh = 0; nh < 4; ++nh) oacc[nh][r] *= ct;
        }
        // pack P to bf16 words: Wp[ni][h] = {s=16ni+4lk+2h, +1} at q=lr
        unsigned Wp[4][2];
        #pragma unroll
        for (int ni = 0; ni < 4; ++ni) {
            Wp[ni][0] = cvtpk(sa[ni][0], sa[ni][1]);
            Wp[ni][1] = cvtpk(sa[ni][2], sa[ni][3]);
        }
        // permute to PV A-frags: pa[kc] word g = P[q=lr][s=32kc+8lk+2g..+1]
        bf16x8 pa[2];
        #pragma unroll
        for (int kc = 0; kc < 2; ++kc) {
            unsigned x0 = Wp[2 * kc][0], y0 = Wp[2 * kc + 1][0];
            PLSWAP32(x0, y0); PLSWAP16(x0, y0);   // x0 -> g0, y0 -> g2
            unsigned x1 = Wp[2 * kc][1], y1 = Wp[2 * kc + 1][1];
            PLSWAP32(x1, y1); PLSWAP16(x1, y1);   // x1 -> g1, y1 -> g3
            unsigned wq[4] = {x0, x1, y0, y1};
            pa[kc] = *(bf16x8*)wq;
        }
        // PV: A = pa (P rows=q), B = V^T  -> D[q=lk*4+r][h=nh*16+lr]
        #pragma unroll
        for (int nh = 0; nh < 4; ++nh) {
            int hrow = nh * 16 + lr;
            #pragma unroll
            for (int kc = 0; kc < 2; ++kc) {
                bf16x8 vb = *(const bf16x8*)
                    &vt[hrow * 256 + ((st * 64 + kc * 32 + lk * 8) ^ ((hrow & 7) << 3))];
                oacc[nh] = __builtin_amdgcn_mfma_f32_16x16x32_bf16(pa[kc], vb, oacc[nh], 0, 0, 0);
            }
        }
    }

    // ---- finalize: reduce per-lane l over lk, transpose, normalize ----
    float lsum = lpart;
    lsum += __shfl_xor(lsum, 16);
    lsum += __shfl_xor(lsum, 32);
    float linv[4];
    #pragma unroll
    for (int r = 0; r < 4; ++r)
        linv[r] = 1.0f / __shfl(lsum, lk * 4 + r);
    #pragma unroll
    for (int nh = 0; nh < 4; ++nh)
        #pragma unroll
        for (int r = 0; r < 4; ++r) {
            size_t row = (size_t)b * TT + q0 + lk * 4 + r;
            out[row * HDIM + nh * 16 + lr] = oacc[nh][r] * linv[r];
        }
}

extern "C" void kernel_launch(void* const* d_in, const int* in_sizes, int n_in,
                              void* d_out, int out_size, void* d_ws, size_t ws_size,
                              hipStream_t stream)
{
    const float* x  = (const float*)d_in[0];
    const float* Wq = (const float*)d_in[1];
    const float* Wk = (const float*)d_in[2];
    const float* Wv = (const float*)d_in[3];
    unsigned short* bt = (unsigned short*)d_ws;   // [192][384] bf16 = 147 KB
    float* out = (float*)d_out;

    prep_bt<<<(NQKV * CDIM + 255) / 256, 256, 0, stream>>>(Wq, Wk, Wv, bt);
    fused<<<BSZ, 1024, 0, stream>>>(x, bt, out);
}